// Round 6
// baseline (54.859 us; speedup 1.0000x reference)
//
#include <hip/hip_runtime.h>
#include <hip/hip_bf16.h>

// Problem constants (fixed by the reference: B=8, N=512, E=128, H=64)
#define BB 8
#define NN 512
#define EE 128
#define HH 64
#define EP (NN * (NN - 1))        // 261632 edges per batch
#define ECNT (BB * EP)            // 2093056 total edges
// d_out layout (floats): [edge_index row0 | edge_index row1 | edge_weights | alpha]
#define OFF_EI0 0
#define OFF_EI1 ECNT
#define OFF_EW  (2 * ECNT)
#define OFF_AL  (3 * ECNT)

// ---------------- Kernel A: pj = h@W1 + b, pkT4 = (h@W2)^T (h-interleaved float4) ----------------
// block = 128 threads (2 waves); each wave computes 8 rows; grid = 4096/16 = 256
// W streamed from L2 (coalesced), h rows via wave-uniform scalar loads.
__global__ __launch_bounds__(128) void k_proj(
        const float* __restrict__ h, const float* __restrict__ W,
        const float* __restrict__ bvec,
        float* __restrict__ pj, float* __restrict__ pkT4f) {
    const int tid  = threadIdx.x;
    const int c    = tid & 63;                  // output column (h)
    const int w    = tid >> 6;                  // wave id 0..1
    const int row0 = blockIdx.x * 16 + w * 8;   // this wave's first row

    const float* h0 = h + (size_t)(row0 + 0) * EE;   // wave-uniform -> s_load
    const float* h1 = h + (size_t)(row0 + 1) * EE;
    const float* h2 = h + (size_t)(row0 + 2) * EE;
    const float* h3 = h + (size_t)(row0 + 3) * EE;
    const float* h4 = h + (size_t)(row0 + 4) * EE;
    const float* h5 = h + (size_t)(row0 + 5) * EE;
    const float* h6 = h + (size_t)(row0 + 6) * EE;
    const float* h7 = h + (size_t)(row0 + 7) * EE;

    float aj0=0.f,aj1=0.f,aj2=0.f,aj3=0.f,aj4=0.f,aj5=0.f,aj6=0.f,aj7=0.f;
    float ak0=0.f,ak1=0.f,ak2=0.f,ak3=0.f,ak4=0.f,ak5=0.f,ak6=0.f,ak7=0.f;

#pragma unroll 8
    for (int e = 0; e < EE; ++e) {
        const float w1 = W[e * HH + c];              // coalesced, L2-resident
        const float w2 = W[(EE + e) * HH + c];
        aj0 = fmaf(h0[e], w1, aj0); ak0 = fmaf(h0[e], w2, ak0);
        aj1 = fmaf(h1[e], w1, aj1); ak1 = fmaf(h1[e], w2, ak1);
        aj2 = fmaf(h2[e], w1, aj2); ak2 = fmaf(h2[e], w2, ak2);
        aj3 = fmaf(h3[e], w1, aj3); ak3 = fmaf(h3[e], w2, ak3);
        aj4 = fmaf(h4[e], w1, aj4); ak4 = fmaf(h4[e], w2, ak4);
        aj5 = fmaf(h5[e], w1, aj5); ak5 = fmaf(h5[e], w2, ak5);
        aj6 = fmaf(h6[e], w1, aj6); ak6 = fmaf(h6[e], w2, ak6);
        aj7 = fmaf(h7[e], w1, aj7); ak7 = fmaf(h7[e], w2, ak7);
    }
    const float bb = bvec[c];

#define PROJ_WRITE(r, ajr, akr) {                                              \
        const int i  = row0 + (r);                                             \
        pj[i * HH + c] = (ajr) + bb;                                           \
        const int bI = i >> 9, n = i & 511;                                    \
        pkT4f[((((size_t)(bI * 16 + (c >> 2))) * NN + n) << 2) + (c & 3)] = (akr); }
    PROJ_WRITE(0, aj0, ak0)
    PROJ_WRITE(1, aj1, ak1)
    PROJ_WRITE(2, aj2, ak2)
    PROJ_WRITE(3, aj3, ak3)
    PROJ_WRITE(4, aj4, ak4)
    PROJ_WRITE(5, aj5, ak5)
    PROJ_WRITE(6, aj6, ak6)
    PROJ_WRITE(7, aj7, ak7)
#undef PROJ_WRITE
}

// ---------------- Kernel B: e = dk + 0.4*sum att|s| (cj row-constant dropped), softmax ----------------
// block = 256 threads = 4 waves; thread owns k0=tid, k1=tid+256; 8 j rows per block.
// pj/att via blockIdx-uniform global reads -> scalar loads; pk in registers; dk computed in-reg.
__global__ __launch_bounds__(256, 2) void k_attn(
        const float* __restrict__ pj, const float4* __restrict__ pkT4,
        const float* __restrict__ att, float* __restrict__ alpha) {
    const int bid   = blockIdx.x;
    const int b     = bid >> 6;
    const int jbase = (bid & 63) * 8;
    const int tid   = threadIdx.x;
    const int lane  = tid & 63;
    const int wid   = tid >> 6;           // 0..3

    __shared__ float e_s[8][NN];          // 16 KB

    // pk rows for k0=tid and k1=tid+256: coalesced dwordx4 loads
    float4 pkA[16], pkB[16];
    const float4* pkb = pkT4 + (size_t)b * 16 * NN + tid;
#pragma unroll
    for (int q = 0; q < 16; ++q) {
        pkA[q] = pkb[q * NN];
        pkB[q] = pkb[q * NN + 256];
    }

    const float4* att4 = reinterpret_cast<const float4*>(att);   // uniform -> s_load

    // dk = 0.6 * sum_h att_h * pk[k][h], from registers
    float dkA = 0.f, dkB = 0.f;
#pragma unroll
    for (int q = 0; q < 16; ++q) {
        const float4 a = att4[q];
        dkA = fmaf(a.x, pkA[q].x, dkA); dkA = fmaf(a.y, pkA[q].y, dkA);
        dkA = fmaf(a.z, pkA[q].z, dkA); dkA = fmaf(a.w, pkA[q].w, dkA);
        dkB = fmaf(a.x, pkB[q].x, dkB); dkB = fmaf(a.y, pkB[q].y, dkB);
        dkB = fmaf(a.z, pkB[q].z, dkB); dkB = fmaf(a.w, pkB[q].w, dkB);
    }
    dkA *= 0.6f; dkB *= 0.6f;

    // pj block slice: blockIdx-uniform base -> scalar (s_load_dwordx4) reads
    const float4* pjb4 = reinterpret_cast<const float4*>(
        pj + ((size_t)b * NN + jbase) * HH);

    float accA[8], accB[8];
#pragma unroll
    for (int j = 0; j < 8; ++j) { accA[j] = 0.f; accB[j] = 0.f; }

#pragma unroll
    for (int q = 0; q < 16; ++q) {
        const float4 af = att4[q];
        const float4 kA = pkA[q];
        const float4 kB = pkB[q];
#pragma unroll
        for (int j = 0; j < 8; ++j) {
            const float4 pw = pjb4[j * 16 + q];   // uniform -> scalar load
            float s;
            s = pw.x + kA.x; accA[j] = fmaf(af.x, fabsf(s), accA[j]);
            s = pw.y + kA.y; accA[j] = fmaf(af.y, fabsf(s), accA[j]);
            s = pw.z + kA.z; accA[j] = fmaf(af.z, fabsf(s), accA[j]);
            s = pw.w + kA.w; accA[j] = fmaf(af.w, fabsf(s), accA[j]);
            s = pw.x + kB.x; accB[j] = fmaf(af.x, fabsf(s), accB[j]);
            s = pw.y + kB.y; accB[j] = fmaf(af.y, fabsf(s), accB[j]);
            s = pw.z + kB.z; accB[j] = fmaf(af.z, fabsf(s), accB[j]);
            s = pw.w + kB.w; accB[j] = fmaf(af.w, fabsf(s), accB[j]);
        }
    }

    // e rows into LDS (cj dropped: softmax is invariant to per-row constants)
#pragma unroll
    for (int j = 0; j < 8; ++j) {
        e_s[j][tid]       = fmaf(0.4f, accA[j], dkA);
        e_s[j][tid + 256] = fmaf(0.4f, accB[j], dkB);
    }
    __syncthreads();

    // softmax: wave wid owns rows {wid, wid+4}
#pragma unroll
    for (int rr = 0; rr < 2; ++rr) {
        const int j = wid + rr * 4;
        float v[8];
        float m = -1e30f;
#pragma unroll
        for (int i2 = 0; i2 < 8; ++i2) {
            v[i2] = e_s[j][lane + 64 * i2];
            m = fmaxf(m, v[i2]);
        }
#pragma unroll
        for (int off = 32; off >= 1; off >>= 1) m = fmaxf(m, __shfl_xor(m, off, 64));
        float s = 0.f;
#pragma unroll
        for (int i2 = 0; i2 < 8; ++i2) { v[i2] = __expf(v[i2] - m); s += v[i2]; }
#pragma unroll
        for (int off = 32; off >= 1; off >>= 1) s += __shfl_xor(s, off, 64);
        const float inv = 1.0f / s;
        float* arow = alpha + ((size_t)b * NN + jbase + j) * NN;
#pragma unroll
        for (int i2 = 0; i2 < 8; ++i2) arow[lane + 64 * i2] = v[i2] * inv;
    }
}

// ---------------- Kernel C: edges, symmetric PAIR of 64x64 tiles per block ----------------
// grid = 8 b * 36 unordered tile pairs (jt<=kt); alpha read exactly once
__global__ void k_edges(const float* __restrict__ alpha, float* __restrict__ out) {
    const int bid = blockIdx.x;
    const int b   = bid / 36;
    int rem = bid - b * 36;
    int jt = 0;
    while (rem >= 8 - jt) { rem -= 8 - jt; ++jt; }   // uniform scalar loop
    const int kt = jt + rem;

    const int jbase = jt * 64;
    const int kbase = kt * 64;
    const int tid   = threadIdx.x;
    const int c     = tid & 63;
    const int r0    = tid >> 6;           // 0..3

    __shared__ float t1[64][65];          // t1[r][c] = A[jbase+r][kbase+c]
    __shared__ float t2[64][65];          // t2[r][c] = A[kbase+r][jbase+c]

    const float* A = alpha + (size_t)b * NN * NN;
    const bool diag = (jt == kt);

#pragma unroll
    for (int i = 0; i < 16; ++i) {
        const int r = i * 4 + r0;
        t1[r][c] = A[(size_t)(jbase + r) * NN + kbase + c];
    }
    if (!diag) {
#pragma unroll
        for (int i = 0; i < 16; ++i) {
            const int r = i * 4 + r0;
            t2[r][c] = A[(size_t)(kbase + r) * NN + jbase + c];
        }
    }
    __syncthreads();

    const float fb = (float)(b * NN);

    // side 1: edges (j = jbase+jj, k = kbase+c)
#pragma unroll
    for (int i = 0; i < 16; ++i) {
        const int jj = i * 4 + r0;
        const int j  = jbase + jj;
        const int k  = kbase + c;
        if (k == j) continue;             // only possible when diag
        const float a_kj = diag ? t1[c][jj] : t2[c][jj];   // padded col read
        const float wv = 0.5f * (t1[jj][c] + a_kj);
        const unsigned t   = (unsigned)k - ((k > j) ? 1u : 0u);
        const unsigned idx = (unsigned)b * EP + (unsigned)j * (NN - 1) + t;
        out[OFF_EI0 + idx] = fb + (float)j;
        out[OFF_EI1 + idx] = fb + (float)k;
        out[OFF_EW  + idx] = wv;
    }

    // side 2: edges (j = kbase+kk, k = jbase+c) — mirrored tile
    if (!diag) {
#pragma unroll
        for (int i = 0; i < 16; ++i) {
            const int kk = i * 4 + r0;
            const int j2 = kbase + kk;
            const int k2 = jbase + c;
            const float wv = 0.5f * (t2[kk][c] + t1[c][kk]);
            const unsigned t   = (unsigned)k2 - ((k2 > j2) ? 1u : 0u);
            const unsigned idx = (unsigned)b * EP + (unsigned)j2 * (NN - 1) + t;
            out[OFF_EI0 + idx] = fb + (float)j2;
            out[OFF_EI1 + idx] = fb + (float)k2;
            out[OFF_EW  + idx] = wv;
        }
    }
}

extern "C" void kernel_launch(void* const* d_in, const int* in_sizes, int n_in,
                              void* d_out, int out_size, void* d_ws, size_t ws_size,
                              hipStream_t stream) {
    const float* h    = (const float*)d_in[0];
    const float* W    = (const float*)d_in[1];
    const float* bvec = (const float*)d_in[2];
    // d_in[3] (att) used only in k_attn
    const float* att  = (const float*)d_in[3];
    float* out = (float*)d_out;

    float* pj   = (float*)d_ws;                      // 1 MB
    float* pkT4 = pj + (size_t)BB * NN * HH;         // 1 MB, h-interleaved float4

    float* alpha = out + OFF_AL;

    k_proj <<<BB * NN / 16, 128, 0, stream>>>(h, W, bvec, pj, pkT4);
    k_attn <<<BB * 64, 256, 0, stream>>>(pj, (const float4*)pkT4, att, alpha);
    k_edges<<<BB * 36, 256, 0, stream>>>(alpha, out);
}

// Round 7
// 43.755 us; speedup vs baseline: 1.2538x; 1.2538x over previous
//
#include <hip/hip_runtime.h>
#include <hip/hip_bf16.h>

// Problem constants (fixed by the reference: B=8, N=512, E=128, H=64)
#define BB 8
#define NN 512
#define EE 128
#define HH 64
#define EP (NN * (NN - 1))        // 261632 edges per batch
#define ECNT (BB * EP)            // 2093056 total edges
// d_out layout (floats): [edge_index row0 | edge_index row1 | edge_weights | alpha]
#define OFF_EI0 0
#define OFF_EI1 ECNT
#define OFF_EW  (2 * ECNT)
#define OFF_AL  (3 * ECNT)

typedef float f16v __attribute__((ext_vector_type(16)));

// ---------------- Kernel A: pj = h@W1 + b, pkT4 = (h@W2)^T (h-interleaved float4) ----------------
// R5-proven structure: block = 256 threads = 4 waves, 8 rows, W staged in LDS (64 KB).
__global__ __launch_bounds__(256) void k_proj(
        const float* __restrict__ h, const float* __restrict__ W,
        const float* __restrict__ bvec,
        float* __restrict__ pj, float* __restrict__ pkT4f) {
    __shared__ float Wl[2 * EE * HH];                // 64 KB
    const int tid = threadIdx.x;

    // stage W: 16384 floats = 4096 float4, 16 per thread, coalesced
    {
        float4* Wl4 = reinterpret_cast<float4*>(Wl);
        const float4* W4 = reinterpret_cast<const float4*>(W);
#pragma unroll
        for (int r = 0; r < 16; ++r) Wl4[r * 256 + tid] = W4[r * 256 + tid];
    }

    const int row0 = blockIdx.x * 8;
    const int c = tid & 63;                          // output column (h)
    const int w = tid >> 6;                          // wave id
    const float* hA = h + (size_t)(row0 + w) * EE;   // wave-uniform -> scalar loads
    const float* hB = h + (size_t)(row0 + w + 4) * EE;
    __syncthreads();

    float aj0 = 0.f, ak0 = 0.f, aj1 = 0.f, ak1 = 0.f;
#pragma unroll
    for (int e = 0; e < EE; ++e) {
        const float w1 = Wl[e * HH + c];             // stride-1 ds_read, conflict-free
        const float w2 = Wl[(EE + e) * HH + c];
        const float h0 = hA[e];
        const float h1 = hB[e];
        aj0 = fmaf(h0, w1, aj0);
        ak0 = fmaf(h0, w2, ak0);
        aj1 = fmaf(h1, w1, aj1);
        ak1 = fmaf(h1, w2, ak1);
    }
    const float bb = bvec[c];
    aj0 += bb; aj1 += bb;

    const int iA = row0 + w;
    const int iB = row0 + w + 4;
    pj[iA * HH + c] = aj0;
    pj[iB * HH + c] = aj1;
    {
        const int bA = iA >> 9, nA = iA & 511;
        const int bB = iB >> 9, nB = iB & 511;
        // h-interleaved float4 transpose: float index = ((b*16 + c/4)*NN + n)*4 + (c&3)
        pkT4f[(((size_t)(bA * 16 + (c >> 2)) * NN + nA) << 2) + (c & 3)] = ak0;
        pkT4f[(((size_t)(bB * 16 + (c >> 2)) * NN + nB) << 2) + (c & 3)] = ak1;
    }
}

// ---------------- Kernel B: e = dk + 0.4*sum att|s|, softmax ----------------
// block = 512 threads = full k row; thread tid <-> k; 8 j rows per block.
// pj rows loaded into SGPRs via explicit s_load_dwordx16 (scalar pipe, zero LDS/VMEM
// in hot loop). pk + att in VGPRs. cj dropped (row-constant, softmax-invariant).
__global__ __launch_bounds__(512) void k_attn(
        const float* __restrict__ pj, const float4* __restrict__ pkT4,
        const float* __restrict__ att, float* __restrict__ alpha) {
    const int bid   = blockIdx.x;
    const int b     = bid >> 6;
    const int jbase = (bid & 63) * 8;
    const int tid   = threadIdx.x;        // = k
    const int lane  = tid & 63;
    const int wid   = tid >> 6;           // 0..7

    __shared__ float e_s[8][NN];          // 16 KB

    // pk row (k = tid): 16 coalesced dwordx4 loads (lanes consecutive)
    float4 pk4[16];
    const float4* pkb = pkT4 + (size_t)b * 16 * NN + tid;
#pragma unroll
    for (int q = 0; q < 16; ++q) pk4[q] = pkb[q * NN];

    // att in VGPRs (uniform values, but keeps SGPR budget for pj rows)
    float4 att4[16];
#pragma unroll
    for (int q = 0; q < 16; ++q) att4[q] = reinterpret_cast<const float4*>(att)[q];

    // dk = 0.6 * sum_h att_h * pk[k][h], in registers
    float dkv = 0.f;
#pragma unroll
    for (int q = 0; q < 16; ++q) {
        dkv = fmaf(att4[q].x, pk4[q].x, dkv);
        dkv = fmaf(att4[q].y, pk4[q].y, dkv);
        dkv = fmaf(att4[q].z, pk4[q].z, dkv);
        dkv = fmaf(att4[q].w, pk4[q].w, dkv);
    }
    dkv *= 0.6f;

    const float* pjrow0 = pj + ((size_t)b * NN + jbase) * HH;   // block-uniform

#pragma unroll
    for (int jj = 0; jj < 8; ++jj) {
        const float* rp = pjrow0 + jj * HH;
        f16v r0, r1, r2, r3;               // 64 SGPRs: one pj row
        asm volatile(
            "s_load_dwordx16 %0, %4, 0x0\n\t"
            "s_load_dwordx16 %1, %4, 0x40\n\t"
            "s_load_dwordx16 %2, %4, 0x80\n\t"
            "s_load_dwordx16 %3, %4, 0xC0\n\t"
            "s_waitcnt lgkmcnt(0)"
            : "=&s"(r0), "=&s"(r1), "=&s"(r2), "=&s"(r3)
            : "s"(rp));
#define PJH(h) ((h) < 16 ? r0[(h) & 15] : (h) < 32 ? r1[(h) & 15] : (h) < 48 ? r2[(h) & 15] : r3[(h) & 15])
        float acc = 0.f;
#pragma unroll
        for (int q = 0; q < 16; ++q) {
            const float4 kv = pk4[q];
            const float4 af = att4[q];
            float s;
            s = PJH(4 * q + 0) + kv.x; acc = fmaf(af.x, fabsf(s), acc);
            s = PJH(4 * q + 1) + kv.y; acc = fmaf(af.y, fabsf(s), acc);
            s = PJH(4 * q + 2) + kv.z; acc = fmaf(af.z, fabsf(s), acc);
            s = PJH(4 * q + 3) + kv.w; acc = fmaf(af.w, fabsf(s), acc);
        }
#undef PJH
        e_s[jj][tid] = fmaf(0.4f, acc, dkv);
    }
    __syncthreads();

    // softmax: wave wid owns row jbase+wid (512 values, 8 per lane)
    {
        float v[8];
        float m = -1e30f;
#pragma unroll
        for (int i2 = 0; i2 < 8; ++i2) {
            v[i2] = e_s[wid][lane + 64 * i2];
            m = fmaxf(m, v[i2]);
        }
#pragma unroll
        for (int off = 32; off >= 1; off >>= 1) m = fmaxf(m, __shfl_xor(m, off, 64));
        float s = 0.f;
#pragma unroll
        for (int i2 = 0; i2 < 8; ++i2) { v[i2] = __expf(v[i2] - m); s += v[i2]; }
#pragma unroll
        for (int off = 32; off >= 1; off >>= 1) s += __shfl_xor(s, off, 64);
        const float inv = 1.0f / s;
        float* arow = alpha + ((size_t)b * NN + jbase + wid) * NN;
#pragma unroll
        for (int i2 = 0; i2 < 8; ++i2) arow[lane + 64 * i2] = v[i2] * inv;
    }
}

// ---------------- Kernel C: edges, symmetric PAIR of 64x64 tiles per block ----------------
// grid = 8 b * 36 unordered tile pairs (jt<=kt); alpha read exactly once
__global__ void k_edges(const float* __restrict__ alpha, float* __restrict__ out) {
    const int bid = blockIdx.x;
    const int b   = bid / 36;
    int rem = bid - b * 36;
    int jt = 0;
    while (rem >= 8 - jt) { rem -= 8 - jt; ++jt; }   // uniform scalar loop
    const int kt = jt + rem;

    const int jbase = jt * 64;
    const int kbase = kt * 64;
    const int tid   = threadIdx.x;
    const int c     = tid & 63;
    const int r0    = tid >> 6;           // 0..3

    __shared__ float t1[64][65];          // t1[r][c] = A[jbase+r][kbase+c]
    __shared__ float t2[64][65];          // t2[r][c] = A[kbase+r][jbase+c]

    const float* A = alpha + (size_t)b * NN * NN;
    const bool diag = (jt == kt);

#pragma unroll
    for (int i = 0; i < 16; ++i) {
        const int r = i * 4 + r0;
        t1[r][c] = A[(size_t)(jbase + r) * NN + kbase + c];
    }
    if (!diag) {
#pragma unroll
        for (int i = 0; i < 16; ++i) {
            const int r = i * 4 + r0;
            t2[r][c] = A[(size_t)(kbase + r) * NN + jbase + c];
        }
    }
    __syncthreads();

    const float fb = (float)(b * NN);

    // side 1: edges (j = jbase+jj, k = kbase+c)
#pragma unroll
    for (int i = 0; i < 16; ++i) {
        const int jj = i * 4 + r0;
        const int j  = jbase + jj;
        const int k  = kbase + c;
        if (k == j) continue;             // only possible when diag
        const float a_kj = diag ? t1[c][jj] : t2[c][jj];   // padded col read
        const float wv = 0.5f * (t1[jj][c] + a_kj);
        const unsigned t   = (unsigned)k - ((k > j) ? 1u : 0u);
        const unsigned idx = (unsigned)b * EP + (unsigned)j * (NN - 1) + t;
        out[OFF_EI0 + idx] = fb + (float)j;
        out[OFF_EI1 + idx] = fb + (float)k;
        out[OFF_EW  + idx] = wv;
    }

    // side 2: edges (j = kbase+kk, k = jbase+c) — mirrored tile
    if (!diag) {
#pragma unroll
        for (int i = 0; i < 16; ++i) {
            const int kk = i * 4 + r0;
            const int j2 = kbase + kk;
            const int k2 = jbase + c;
            const float wv = 0.5f * (t2[kk][c] + t1[c][kk]);
            const unsigned t   = (unsigned)k2 - ((k2 > j2) ? 1u : 0u);
            const unsigned idx = (unsigned)b * EP + (unsigned)j2 * (NN - 1) + t;
            out[OFF_EI0 + idx] = fb + (float)j2;
            out[OFF_EI1 + idx] = fb + (float)k2;
            out[OFF_EW  + idx] = wv;
        }
    }
}

extern "C" void kernel_launch(void* const* d_in, const int* in_sizes, int n_in,
                              void* d_out, int out_size, void* d_ws, size_t ws_size,
                              hipStream_t stream) {
    const float* h    = (const float*)d_in[0];
    const float* W    = (const float*)d_in[1];
    const float* bvec = (const float*)d_in[2];
    const float* att  = (const float*)d_in[3];
    float* out = (float*)d_out;

    float* pj   = (float*)d_ws;                      // 1 MB
    float* pkT4 = pj + (size_t)BB * NN * HH;         // 1 MB, h-interleaved float4

    float* alpha = out + OFF_AL;

    k_proj <<<BB * NN / 8, 256, 0, stream>>>(h, W, bvec, pj, pkT4);
    k_attn <<<BB * 64, 512, 0, stream>>>(pj, (const float4*)pkT4, att, alpha);
    k_edges<<<BB * 36, 256, 0, stream>>>(alpha, out);
}